// Round 5
// baseline (153.078 us; speedup 1.0000x reference)
//
#include <hip/hip_runtime.h>
#include <hip/hip_bf16.h>
#include <hip/hip_fp16.h>

// Problem constants
#define GN 28
// ws layout: per-g contiguous 12288-byte tile, pre-swizzled for LDS staging:
//   [ W1 f16 [n=64][k=64] 8KiB | W2 f16 [n2=32][kk=64] K-permuted 4KiB ]
// byte = n*128 + 2k, XOR-swizzled ^((n&7)<<4)   (byte-identical to r2..r4 layout)
#define G_TILE_BYTES 12288
#define WS_BYTES (GN * G_TILE_BYTES)   // 344064

typedef __attribute__((ext_vector_type(4))) float f32x4;
typedef __attribute__((ext_vector_type(8))) short short8;
typedef _Float16 f16x8 __attribute__((ext_vector_type(8)));

__device__ __forceinline__ unsigned short f2h(float v){
  __half h = __float2half(v);   // RNE
  return __builtin_bit_cast(unsigned short, h);
}
__device__ __forceinline__ f32x4 mfma16f(short8 a, short8 b, f32x4 c){
  return __builtin_amdgcn_mfma_f32_16x16x32_f16(
      __builtin_bit_cast(f16x8, a), __builtin_bit_cast(f16x8, b), c, 0, 0, 0);
}

// ---------------------------------------------------------------------------
// Prologue (unchanged from round 4, hardware-verified): one block per g,
// coalesced reads, LDS transpose (+1 pad), packed uint4 swizzle-safe stores.
// W2 K-permuted so layer-1 D-fragments feed layer-2 B directly:
//   MFMA k-slot kk = ks*32 + q*8 + u*4 + i  carries  kn = 32*ks + 16*u + 4*q + i
// ---------------------------------------------------------------------------
__global__ __launch_bounds__(256) void prep_weights(
    const float* __restrict__ W1, const float* __restrict__ W2,
    unsigned char* __restrict__ ws){
  __shared__ float t1[64*65];   // W1[g] transposed staging, padded
  __shared__ float t2[64*33];   // W2[g] staging, padded
  const int g = blockIdx.x;
  const int tid = threadIdx.x;

  {
    const f32x4* src = (const f32x4*)(W1 + g*4096);
    int k = tid >> 2, n0 = (tid & 3) * 16;
    #pragma unroll
    for (int j = 0; j < 4; ++j){
      f32x4 v = src[tid*4 + j];
      #pragma unroll
      for (int e = 0; e < 4; ++e) t1[k*65 + n0 + j*4 + e] = v[e];
    }
  }
  {
    const f32x4* src = (const f32x4*)(W2 + g*2048);
    int k = tid >> 2, n0 = (tid & 3) * 8;
    #pragma unroll
    for (int j = 0; j < 2; ++j){
      f32x4 v = src[tid*2 + j];
      #pragma unroll
      for (int e = 0; e < 4; ++e) t2[k*33 + n0 + j*4 + e] = v[e];
    }
  }
  __syncthreads();

  unsigned char* base = ws + g*G_TILE_BYTES;
  {
    int n = tid & 63, mh = tid >> 6;
    #pragma unroll
    for (int h = 0; h < 2; ++h){
      unsigned w[4];
      #pragma unroll
      for (int mm = 0; mm < 4; ++mm){
        int m = mh*8 + h*4 + mm;          // k-pair index
        float lo = t1[(2*m    )*65 + n];
        float hi = t1[(2*m + 1)*65 + n];
        w[mm] = (unsigned)f2h(lo) | ((unsigned)f2h(hi) << 16);
      }
      int off = (n*128 + mh*32 + h*16) ^ ((n & 7) << 4);
      *(uint4*)(base + off) = make_uint4(w[0], w[1], w[2], w[3]);
    }
  }
  {
    int n2 = tid & 31, mq = tid >> 5;
    unsigned w[4];
    #pragma unroll
    for (int mm = 0; mm < 4; ++mm){
      int m = mq*4 + mm;
      int kk = 2*m;
      int ks = kk >> 5, qq = (kk >> 3) & 3, u = (kk >> 2) & 1, i = kk & 3;
      int kn = 32*ks + 16*u + 4*qq + i;   // kk,kk+1 -> kn,kn+1
      float lo = t2[(kn    )*33 + n2];
      float hi = t2[(kn + 1)*33 + n2];
      w[mm] = (unsigned)f2h(lo) | ((unsigned)f2h(hi) << 16);
    }
    int off = (n2*128 + mq*16) ^ ((n2 & 7) << 4);
    *(uint4*)(base + 8192 + off) = make_uint4(w[0], w[1], w[2], w[3]);
  }
}

// ---------------------------------------------------------------------------
// Main fused kernel, round 5: 1024 blocks x 128 threads (2 waves), 128 rows
// per block, 64 rows/wave. 4 independent blocks/CU, 8 waves/CU -> per-CU LDS
// weight re-read traffic halved vs r4, and barrier couples only 2 waves.
// LDS holds ONLY the double-buffered 12 KiB weight tile: biases/W3 read from
// global (L2-hot) each g and folded into the relu/pack VALU phase; acc init
// from a loop-invariant zero register; b3[g] is wave-uniform -> s_load.
// ---------------------------------------------------------------------------
__global__ __launch_bounds__(128, 2) void mlp_fused(
    const float* __restrict__ x,  const float* __restrict__ b1,
    const float* __restrict__ b2, const float* __restrict__ W3,
    const float* __restrict__ b3, const unsigned char* __restrict__ ws,
    float* __restrict__ out){
  __shared__ uint4 wbuf[2][768];        // 2 x 12 KiB weight tile (all the LDS)

  const int tid = threadIdx.x;
  const int wv  = tid >> 6;             // 0..1
  const int ln  = tid & 63;
  const int l15 = ln & 15;
  const int q   = ln >> 4;
  const int rowBase = blockIdx.x * 128 + wv * 64;

  // ---- x B-fragments (f16), loaded once, reused for all 28 g ----
  short8 xf[4][2];
  #pragma unroll
  for (int rt = 0; rt < 4; ++rt)
    #pragma unroll
    for (int ks = 0; ks < 2; ++ks){
      const float* p = x + (rowBase + rt*16 + l15)*64 + ks*32 + q*8;
      f32x4 a = *(const f32x4*)p;
      f32x4 b = *(const f32x4*)(p + 4);
      short8 s;
      #pragma unroll
      for (int j = 0; j < 4; ++j){
        s[j]   = (short)f2h(a[j]);
        s[4+j] = (short)f2h(b[j]);
      }
      xf[rt][ks] = s;
    }

  // ---- staging: wave wv copies its 6 KiB slice of g's 12 KiB tile ----
  auto stage = [&](int g, int buf){
    const unsigned char* gb = ws + g*G_TILE_BYTES + wv*6144 + ln*16;
    uint4* lb = &wbuf[buf][wv*384];
    #pragma unroll
    for (int it = 0; it < 6; ++it){
      __builtin_amdgcn_global_load_lds(
          (const __attribute__((address_space(1))) void*)(gb + it*1024),
          (__attribute__((address_space(3))) void*)(lb + it*64), 16, 0, 0);
    }
  };

  stage(0, 0);
  asm volatile("s_waitcnt vmcnt(0)" ::: "memory");
  __syncthreads();

  const f32x4 z4 = {0.f, 0.f, 0.f, 0.f};   // loop-invariant zero C-operand

  for (int g = 0; g < GN; ++g){
    const int cur = g & 1;
    if (g + 1 < GN) stage(g + 1, cur ^ 1);
    const uint4* wb = wbuf[cur];

    // bias/W3 fragments from global (L2-hot; >=16 MFMAs of slack before use)
    f32x4 bias1v[4], bias2v[2], w3v[2];
    #pragma unroll
    for (int nt = 0; nt < 4; ++nt)
      bias1v[nt] = *(const f32x4*)(b1 + g*64 + nt*16 + q*4);
    #pragma unroll
    for (int nt = 0; nt < 2; ++nt){
      bias2v[nt] = *(const f32x4*)(b2 + g*32 + nt*16 + q*4);
      w3v[nt]    = *(const f32x4*)(W3 + g*32 + nt*16 + q*4);
    }
    float bias3 = b3[g];                 // uniform -> s_load

    // ---------------- layer 1: h1T[n=64][r=64/wave] ----------------
    short8 a1[4][2];
    #pragma unroll
    for (int nt = 0; nt < 4; ++nt)
      #pragma unroll
      for (int ks = 0; ks < 2; ++ks){
        int n = nt*16 + l15;
        int off = ((n*128 + ks*64 + q*16) ^ ((n & 7) << 4)) >> 4;
        a1[nt][ks] = __builtin_bit_cast(short8, wb[off]);
      }
    f32x4 acc1[4][4];
    #pragma unroll
    for (int nt = 0; nt < 4; ++nt)
      #pragma unroll
      for (int rt = 0; rt < 4; ++rt){
        acc1[nt][rt] = mfma16f(a1[nt][0], xf[rt][0], z4);
        acc1[nt][rt] = mfma16f(a1[nt][1], xf[rt][1], acc1[nt][rt]);
      }

    // ---- h1 bias+relu -> f16, packed IN REGISTERS as layer-2 B-frags ----
    // k-slot (ks, q*8+u*4+i) carries n = 32ks+16u+4q+i == acc1[2ks+u][rt][i]
    short8 bh[4][2];
    #pragma unroll
    for (int rt = 0; rt < 4; ++rt)
      #pragma unroll
      for (int ks = 0; ks < 2; ++ks){
        f32x4 v0 = acc1[2*ks][rt]     + bias1v[2*ks];
        f32x4 v1 = acc1[2*ks + 1][rt] + bias1v[2*ks + 1];
        short8 h;
        #pragma unroll
        for (int i = 0; i < 4; ++i){
          h[i]   = (short)f2h(fmaxf(v0[i], 0.0f));
          h[4+i] = (short)f2h(fmaxf(v1[i], 0.0f));
        }
        bh[rt][ks] = h;
      }

    // ---------------- layer 2: h2T[n2=32][r=64/wave] ----------------
    short8 a2[2][2];
    #pragma unroll
    for (int nt = 0; nt < 2; ++nt)
      #pragma unroll
      for (int ks = 0; ks < 2; ++ks){
        int n2 = nt*16 + l15;
        int off = ((n2*128 + ks*64 + q*16) ^ ((n2 & 7) << 4)) >> 4;
        a2[nt][ks] = __builtin_bit_cast(short8, wb[512 + off]);
      }
    f32x4 acc2[2][4];
    #pragma unroll
    for (int nt = 0; nt < 2; ++nt)
      #pragma unroll
      for (int rt = 0; rt < 4; ++rt){
        acc2[nt][rt] = mfma16f(a2[nt][0], bh[rt][0], z4);
        acc2[nt][rt] = mfma16f(a2[nt][1], bh[rt][1], acc2[nt][rt]);
      }

    // ---------------- layer 3: bias+relu, in-register dot, reduce ----------------
    #pragma unroll
    for (int rt = 0; rt < 4; ++rt){
      float p = 0.0f;
      #pragma unroll
      for (int nt = 0; nt < 2; ++nt){
        f32x4 v = acc2[nt][rt] + bias2v[nt];
        #pragma unroll
        for (int i = 0; i < 4; ++i)
          p = fmaf(fmaxf(v[i], 0.0f), w3v[nt][i], p);
      }
      p += __shfl_xor(p, 16);
      p += __shfl_xor(p, 32);
      p += bias3;
      if (ln < 16)
        out[(rowBase + rt*16 + ln)*28 + g] = p;
    }

    // drain stage (and bias) loads, then barrier: buf[cur^1] ready, buf[cur] free
    asm volatile("s_waitcnt vmcnt(0)" ::: "memory");
    __syncthreads();
  }
}

extern "C" void kernel_launch(void* const* d_in, const int* in_sizes, int n_in,
                              void* d_out, int out_size, void* d_ws, size_t ws_size,
                              hipStream_t stream){
  const float* x  = (const float*)d_in[0];
  const float* W1 = (const float*)d_in[1];
  const float* b1 = (const float*)d_in[2];
  const float* W2 = (const float*)d_in[3];
  const float* b2 = (const float*)d_in[4];
  const float* W3 = (const float*)d_in[5];
  const float* b3 = (const float*)d_in[6];
  unsigned char* ws = (unsigned char*)d_ws;
  float* out = (float*)d_out;
  if (ws_size < (size_t)WS_BYTES) return;
  hipLaunchKernelGGL(prep_weights, dim3(GN), dim3(256), 0, stream, W1, W2, ws);
  hipLaunchKernelGGL(mlp_fused, dim3(1024), dim3(128), 0, stream,
                     x, b1, b2, W3, b3, ws, out);
}

// Round 7
// 151.344 us; speedup vs baseline: 1.0115x; 1.0115x over previous
//
#include <hip/hip_runtime.h>
#include <hip/hip_bf16.h>
#include <hip/hip_fp16.h>

// Problem constants
#define GN 28
// ws layout: per-g contiguous 12288-byte tile, pre-swizzled for LDS staging:
//   [ W1 f16 [n=64][k=64] 8KiB | W2 f16 [n2=32][kk=64] K-permuted 4KiB ]
// byte = n*128 + 2k, XOR-swizzled ^((n&7)<<4)   (byte-identical to r2..r5 layout)
#define G_TILE_BYTES 12288
#define WS_BYTES (GN * G_TILE_BYTES)   // 344064

typedef __attribute__((ext_vector_type(4))) float f32x4;
typedef __attribute__((ext_vector_type(8))) short short8;
typedef _Float16 f16x8 __attribute__((ext_vector_type(8)));
typedef __fp16 pk16x2 __attribute__((ext_vector_type(2)));   // cvt_pkrtz result type

__device__ __forceinline__ unsigned short f2h(float v){
  __half h = __float2half(v);   // RNE
  return __builtin_bit_cast(unsigned short, h);
}
__device__ __forceinline__ f32x4 mfma16f(short8 a, short8 b, f32x4 c){
  return __builtin_amdgcn_mfma_f32_16x16x32_f16(
      __builtin_bit_cast(f16x8, a), __builtin_bit_cast(f16x8, b), c, 0, 0, 0);
}

// ---------------------------------------------------------------------------
// Prologue (unchanged, hardware-verified): one block per g, coalesced reads,
// LDS transpose (+1 pad), packed uint4 swizzle-safe stores.
// W2 K-permuted so layer-1 D-fragments feed layer-2 B directly:
//   MFMA k-slot kk = ks*32 + q*8 + u*4 + i  carries  kn = 32*ks + 16*u + 4*q + i
// ---------------------------------------------------------------------------
__global__ __launch_bounds__(256) void prep_weights(
    const float* __restrict__ W1, const float* __restrict__ W2,
    unsigned char* __restrict__ ws){
  __shared__ float t1[64*65];   // W1[g] transposed staging, padded
  __shared__ float t2[64*33];   // W2[g] staging, padded
  const int g = blockIdx.x;
  const int tid = threadIdx.x;

  {
    const f32x4* src = (const f32x4*)(W1 + g*4096);
    int k = tid >> 2, n0 = (tid & 3) * 16;
    #pragma unroll
    for (int j = 0; j < 4; ++j){
      f32x4 v = src[tid*4 + j];
      #pragma unroll
      for (int e = 0; e < 4; ++e) t1[k*65 + n0 + j*4 + e] = v[e];
    }
  }
  {
    const f32x4* src = (const f32x4*)(W2 + g*2048);
    int k = tid >> 2, n0 = (tid & 3) * 8;
    #pragma unroll
    for (int j = 0; j < 2; ++j){
      f32x4 v = src[tid*2 + j];
      #pragma unroll
      for (int e = 0; e < 4; ++e) t2[k*33 + n0 + j*4 + e] = v[e];
    }
  }
  __syncthreads();

  unsigned char* base = ws + g*G_TILE_BYTES;
  {
    int n = tid & 63, mh = tid >> 6;
    #pragma unroll
    for (int h = 0; h < 2; ++h){
      unsigned w[4];
      #pragma unroll
      for (int mm = 0; mm < 4; ++mm){
        int m = mh*8 + h*4 + mm;          // k-pair index
        float lo = t1[(2*m    )*65 + n];
        float hi = t1[(2*m + 1)*65 + n];
        w[mm] = (unsigned)f2h(lo) | ((unsigned)f2h(hi) << 16);
      }
      int off = (n*128 + mh*32 + h*16) ^ ((n & 7) << 4);
      *(uint4*)(base + off) = make_uint4(w[0], w[1], w[2], w[3]);
    }
  }
  {
    int n2 = tid & 31, mq = tid >> 5;
    unsigned w[4];
    #pragma unroll
    for (int mm = 0; mm < 4; ++mm){
      int m = mq*4 + mm;
      int kk = 2*m;
      int ks = kk >> 5, qq = (kk >> 3) & 3, u = (kk >> 2) & 1, i = kk & 3;
      int kn = 32*ks + 16*u + 4*qq + i;   // kk,kk+1 -> kn,kn+1
      float lo = t2[(kn    )*33 + n2];
      float hi = t2[(kn + 1)*33 + n2];
      w[mm] = (unsigned)f2h(lo) | ((unsigned)f2h(hi) << 16);
    }
    int off = (n2*128 + mq*16) ^ ((n2 & 7) << 4);
    *(uint4*)(base + 8192 + off) = make_uint4(w[0], w[1], w[2], w[3]);
  }
}

// ---------------------------------------------------------------------------
// Main fused kernel, round 7 (= round-6 design, cvt_pkrtz type fixed):
// cross-g SOFTWARE PIPELINE. 1024 blocks x 128 threads (2 waves), 64 rows
// per wave. Triple-buffered weight LDS: at body(g), buffers for g AND g+1
// are both staged, so layer-1 MFMAs of g+1 (pure MFMA stream) interleave
// with pack/L2/L3 of g (VALU stream) — no barrier between them. Biases ride
// the MFMA C-operand; f32->f16 via cvt_pkrtz pairs. Two named acc sets
// (A/B) swapped by a 2-unrolled loop keep register indexing static.
// ---------------------------------------------------------------------------
__global__ __launch_bounds__(128, 2) void mlp_fused(
    const float* __restrict__ x,  const float* __restrict__ b1,
    const float* __restrict__ b2, const float* __restrict__ W3,
    const float* __restrict__ b3, const unsigned char* __restrict__ ws,
    float* __restrict__ out){
  __shared__ uint4 wbuf[3][768];        // 3 x 12 KiB weight tile

  const int tid = threadIdx.x;
  const int wv  = tid >> 6;             // 0..1
  const int ln  = tid & 63;
  const int l15 = ln & 15;
  const int q   = ln >> 4;
  const int rowBase = blockIdx.x * 128 + wv * 64;

  // ---- x B-fragments (f16), loaded once, reused for all 28 g ----
  short8 xf[4][2];
  #pragma unroll
  for (int rt = 0; rt < 4; ++rt)
    #pragma unroll
    for (int ks = 0; ks < 2; ++ks){
      const float* p = x + (rowBase + rt*16 + l15)*64 + ks*32 + q*8;
      f32x4 a = *(const f32x4*)p;
      f32x4 b = *(const f32x4*)(p + 4);
      short8 s;
      #pragma unroll
      for (int j = 0; j < 4; ++j){
        s[j]   = (short)f2h(a[j]);
        s[4+j] = (short)f2h(b[j]);
      }
      xf[rt][ks] = s;
    }

  // ---- hoisted swizzled fragment offsets (g-invariant, uint4 units) ----
  int offA1[4][2], offA2[2][2];
  #pragma unroll
  for (int nt = 0; nt < 4; ++nt)
    #pragma unroll
    for (int ks = 0; ks < 2; ++ks){
      int n = nt*16 + l15;
      offA1[nt][ks] = ((n*128 + ks*64 + q*16) ^ ((n & 7) << 4)) >> 4;
    }
  #pragma unroll
  for (int nt = 0; nt < 2; ++nt)
    #pragma unroll
    for (int ks = 0; ks < 2; ++ks){
      int n2 = nt*16 + l15;
      offA2[nt][ks] = (((n2*128 + ks*64 + q*16) ^ ((n2 & 7) << 4)) >> 4) + 512;
    }

  // ---- staging: wave wv copies its 6 KiB slice of g's 12 KiB tile ----
  auto stage = [&](int g, int buf){
    const unsigned char* gb = ws + g*G_TILE_BYTES + wv*6144 + ln*16;
    uint4* lb = &wbuf[buf][wv*384];
    #pragma unroll
    for (int it = 0; it < 6; ++it){
      __builtin_amdgcn_global_load_lds(
          (const __attribute__((address_space(1))) void*)(gb + it*1024),
          (__attribute__((address_space(3))) void*)(lb + it*64), 16, 0, 0);
    }
  };

  // relu + f32->f16 pack (pkrtz pairs), h[0..3]<-v0, h[4..7]<-v1
  auto packrelu = [&](const f32x4& v0, const f32x4& v1) -> short8 {
    union { unsigned u[4]; short8 s; } r;
    pk16x2 t0 = __builtin_amdgcn_cvt_pkrtz(fmaxf(v0[0],0.f), fmaxf(v0[1],0.f));
    pk16x2 t1 = __builtin_amdgcn_cvt_pkrtz(fmaxf(v0[2],0.f), fmaxf(v0[3],0.f));
    pk16x2 t2 = __builtin_amdgcn_cvt_pkrtz(fmaxf(v1[0],0.f), fmaxf(v1[1],0.f));
    pk16x2 t3 = __builtin_amdgcn_cvt_pkrtz(fmaxf(v1[2],0.f), fmaxf(v1[3],0.f));
    r.u[0] = __builtin_bit_cast(unsigned, t0);
    r.u[1] = __builtin_bit_cast(unsigned, t1);
    r.u[2] = __builtin_bit_cast(unsigned, t2);
    r.u[3] = __builtin_bit_cast(unsigned, t3);
    return r.s;
  };

  f32x4 accA[4][4], accB[4][4];

  // ---- prologue: fill pipeline ----
  stage(0, 0);
  f32x4 b1c[4];
  #pragma unroll
  for (int nt = 0; nt < 4; ++nt)
    b1c[nt] = *(const f32x4*)(b1 + 0*64 + nt*16 + q*4);
  asm volatile("s_waitcnt vmcnt(0)" ::: "memory");
  __syncthreads();                       // buf0 ready
  stage(1, 1);                           // in flight during L1(0)
  {
    short8 a1f[4][2];
    #pragma unroll
    for (int nt = 0; nt < 4; ++nt)
      #pragma unroll
      for (int ks = 0; ks < 2; ++ks)
        a1f[nt][ks] = __builtin_bit_cast(short8, wbuf[0][offA1[nt][ks]]);
    #pragma unroll
    for (int nt = 0; nt < 4; ++nt)
      #pragma unroll
      for (int rt = 0; rt < 4; ++rt){
        accA[nt][rt] = mfma16f(a1f[nt][0], xf[rt][0], b1c[nt]);
        accA[nt][rt] = mfma16f(a1f[nt][1], xf[rt][1], accA[nt][rt]);
      }
  }
  asm volatile("s_waitcnt vmcnt(0)" ::: "memory");
  __syncthreads();                       // buf1 ready

  // ---- pipelined body: consumes accC (branch g), produces accN (branch g+1) ----
  auto body = [&](int g, f32x4 (&accC)[4][4], f32x4 (&accN)[4][4]){
    const int gn = (g + 1 < GN) ? g + 1 : GN - 1;   // clamped (dummy on last)
    if (g + 2 < GN) stage(g + 2, (g + 2) % 3);
    const uint4* wbN = wbuf[gn % 3];
    const uint4* wbC = wbuf[g % 3];

    // ---- MFMA stream: layer-1 of g+1 (independent of VALU stream below) ----
    f32x4 b1N[4];
    #pragma unroll
    for (int nt = 0; nt < 4; ++nt)
      b1N[nt] = *(const f32x4*)(b1 + gn*64 + nt*16 + q*4);
    short8 a1n[4][2];
    #pragma unroll
    for (int nt = 0; nt < 4; ++nt)
      #pragma unroll
      for (int ks = 0; ks < 2; ++ks)
        a1n[nt][ks] = __builtin_bit_cast(short8, wbN[offA1[nt][ks]]);
    #pragma unroll
    for (int nt = 0; nt < 4; ++nt)
      #pragma unroll
      for (int rt = 0; rt < 4; ++rt){
        accN[nt][rt] = mfma16f(a1n[nt][0], xf[rt][0], b1N[nt]);
        accN[nt][rt] = mfma16f(a1n[nt][1], xf[rt][1], accN[nt][rt]);
      }

    // ---- VALU stream: pack(g) -> L2 -> L3 ----
    // k-slot (ks, q*8+u*4+i) carries n = 32ks+16u+4q+i == accC[2ks+u][rt][i]
    short8 bh[4][2];
    #pragma unroll
    for (int rt = 0; rt < 4; ++rt)
      #pragma unroll
      for (int ks = 0; ks < 2; ++ks)
        bh[rt][ks] = packrelu(accC[2*ks][rt], accC[2*ks + 1][rt]);

    f32x4 b2v[2], w3v[2];
    #pragma unroll
    for (int nt = 0; nt < 2; ++nt){
      b2v[nt] = *(const f32x4*)(b2 + g*32 + nt*16 + q*4);
      w3v[nt] = *(const f32x4*)(W3 + g*32 + nt*16 + q*4);
    }
    short8 a2[2][2];
    #pragma unroll
    for (int nt = 0; nt < 2; ++nt)
      #pragma unroll
      for (int ks = 0; ks < 2; ++ks)
        a2[nt][ks] = __builtin_bit_cast(short8, wbC[offA2[nt][ks]]);
    f32x4 acc2[2][4];
    #pragma unroll
    for (int nt = 0; nt < 2; ++nt)
      #pragma unroll
      for (int rt = 0; rt < 4; ++rt){
        acc2[nt][rt] = mfma16f(a2[nt][0], bh[rt][0], b2v[nt]);
        acc2[nt][rt] = mfma16f(a2[nt][1], bh[rt][1], acc2[nt][rt]);
      }

    float bias3 = b3[g];
    #pragma unroll
    for (int rt = 0; rt < 4; ++rt){
      float p = 0.0f;
      #pragma unroll
      for (int nt = 0; nt < 2; ++nt)
        #pragma unroll
        for (int i = 0; i < 4; ++i)
          p = fmaf(fmaxf(acc2[nt][rt][i], 0.0f), w3v[nt][i], p);
      p += __shfl_xor(p, 16);
      p += __shfl_xor(p, 32);
      p += bias3;
      if (ln < 16)
        out[(rowBase + rt*16 + ln)*28 + g] = p;
    }

    // drain stage(g+2) (+bias loads), then barrier: buffer (g+2)%3 ready,
    // and everyone is done reading buffer g%3 before body(g+1) stages into it.
    asm volatile("s_waitcnt vmcnt(0)" ::: "memory");
    __syncthreads();
  };

  for (int gg = 0; gg < GN; gg += 2){
    body(gg,     accA, accB);
    body(gg + 1, accB, accA);
  }
}

extern "C" void kernel_launch(void* const* d_in, const int* in_sizes, int n_in,
                              void* d_out, int out_size, void* d_ws, size_t ws_size,
                              hipStream_t stream){
  const float* x  = (const float*)d_in[0];
  const float* W1 = (const float*)d_in[1];
  const float* b1 = (const float*)d_in[2];
  const float* W2 = (const float*)d_in[3];
  const float* b2 = (const float*)d_in[4];
  const float* W3 = (const float*)d_in[5];
  const float* b3 = (const float*)d_in[6];
  unsigned char* ws = (unsigned char*)d_ws;
  float* out = (float*)d_out;
  if (ws_size < (size_t)WS_BYTES) return;
  hipLaunchKernelGGL(prep_weights, dim3(GN), dim3(256), 0, stream, W1, W2, ws);
  hipLaunchKernelGGL(mlp_fused, dim3(1024), dim3(128), 0, stream,
                     x, b1, b2, W3, b3, ws, out);
}

// Round 8
// 144.296 us; speedup vs baseline: 1.0609x; 1.0488x over previous
//
#include <hip/hip_runtime.h>
#include <hip/hip_bf16.h>
#include <hip/hip_fp16.h>

// Problem constants
#define GN 28
// ws layout: per-g contiguous 12288-byte tile, pre-swizzled for LDS staging:
//   [ W1 f16 [n=64][k=64] 8KiB | W2 f16 [n2=32][kk=64] K-permuted 4KiB ]
// byte = n*128 + 2k, XOR-swizzled ^((n&7)<<4)   (byte-identical to r2..r7 layout)
#define G_TILE_BYTES 12288
#define WS_BYTES (GN * G_TILE_BYTES)   // 344064

typedef __attribute__((ext_vector_type(4))) float f32x4;
typedef __attribute__((ext_vector_type(8))) short short8;
typedef _Float16 f16x8 __attribute__((ext_vector_type(8)));
typedef __fp16 pk16x2 __attribute__((ext_vector_type(2)));   // cvt_pkrtz result type

__device__ __forceinline__ unsigned short f2h(float v){
  __half h = __float2half(v);   // RNE
  return __builtin_bit_cast(unsigned short, h);
}
__device__ __forceinline__ f32x4 mfma16f(short8 a, short8 b, f32x4 c){
  return __builtin_amdgcn_mfma_f32_16x16x32_f16(
      __builtin_bit_cast(f16x8, a), __builtin_bit_cast(f16x8, b), c, 0, 0, 0);
}

// ---------------------------------------------------------------------------
// Prologue (unchanged, hardware-verified since r4): one block per g,
// coalesced reads, LDS transpose (+1 pad), packed uint4 swizzle-safe stores.
// W2 K-permuted so layer-1 D-fragments feed layer-2 B directly:
//   MFMA k-slot kk = ks*32 + q*8 + u*4 + i  carries  kn = 32*ks + 16*u + 4*q + i
// ---------------------------------------------------------------------------
__global__ __launch_bounds__(256) void prep_weights(
    const float* __restrict__ W1, const float* __restrict__ W2,
    unsigned char* __restrict__ ws){
  __shared__ float t1[64*65];   // W1[g] transposed staging, padded
  __shared__ float t2[64*33];   // W2[g] staging, padded
  const int g = blockIdx.x;
  const int tid = threadIdx.x;

  {
    const f32x4* src = (const f32x4*)(W1 + g*4096);
    int k = tid >> 2, n0 = (tid & 3) * 16;
    #pragma unroll
    for (int j = 0; j < 4; ++j){
      f32x4 v = src[tid*4 + j];
      #pragma unroll
      for (int e = 0; e < 4; ++e) t1[k*65 + n0 + j*4 + e] = v[e];
    }
  }
  {
    const f32x4* src = (const f32x4*)(W2 + g*2048);
    int k = tid >> 2, n0 = (tid & 3) * 8;
    #pragma unroll
    for (int j = 0; j < 2; ++j){
      f32x4 v = src[tid*2 + j];
      #pragma unroll
      for (int e = 0; e < 4; ++e) t2[k*33 + n0 + j*4 + e] = v[e];
    }
  }
  __syncthreads();

  unsigned char* base = ws + g*G_TILE_BYTES;
  {
    int n = tid & 63, mh = tid >> 6;
    #pragma unroll
    for (int h = 0; h < 2; ++h){
      unsigned w[4];
      #pragma unroll
      for (int mm = 0; mm < 4; ++mm){
        int m = mh*8 + h*4 + mm;          // k-pair index
        float lo = t1[(2*m    )*65 + n];
        float hi = t1[(2*m + 1)*65 + n];
        w[mm] = (unsigned)f2h(lo) | ((unsigned)f2h(hi) << 16);
      }
      int off = (n*128 + mh*32 + h*16) ^ ((n & 7) << 4);
      *(uint4*)(base + off) = make_uint4(w[0], w[1], w[2], w[3]);
    }
  }
  {
    int n2 = tid & 31, mq = tid >> 5;
    unsigned w[4];
    #pragma unroll
    for (int mm = 0; mm < 4; ++mm){
      int m = mq*4 + mm;
      int kk = 2*m;
      int ks = kk >> 5, qq = (kk >> 3) & 3, u = (kk >> 2) & 1, i = kk & 3;
      int kn = 32*ks + 16*u + 4*qq + i;   // kk,kk+1 -> kn,kn+1
      float lo = t2[(kn    )*33 + n2];
      float hi = t2[(kn + 1)*33 + n2];
      w[mm] = (unsigned)f2h(lo) | ((unsigned)f2h(hi) << 16);
    }
    int off = (n2*128 + mq*16) ^ ((n2 & 7) << 4);
    *(uint4*)(base + 8192 + off) = make_uint4(w[0], w[1], w[2], w[3]);
  }
}

// ---------------------------------------------------------------------------
// Main fused kernel, round 8 = r4 structure (best measured) with ZERO global
// stores inside the g-loop: per-g results staged in LDS outb, single
// coalesced writeout at the end. The in-loop vmcnt(0) now covers only stage
// + bias loads (no scatter-store retirement). b1 bias C-operands prefetched
// one g ahead via ping-pong register sets (2-unrolled loop, static indexing).
// 1024 blocks x 256 threads (4 waves), 128 rows/block, 32 rows/wave,
// LDS 38.9 KiB -> 4 blocks/CU.
// ---------------------------------------------------------------------------
__global__ __launch_bounds__(256, 4) void mlp_fused(
    const float* __restrict__ x,  const float* __restrict__ b1,
    const float* __restrict__ b2, const float* __restrict__ W3,
    const float* __restrict__ b3, const unsigned char* __restrict__ ws,
    float* __restrict__ out){
  __shared__ uint4 wbuf[2][768];        // 2 x 12 KiB weight tile
  __shared__ float outb[128*28];        // 14 KiB result staging

  const int tid = threadIdx.x;
  const int wv  = tid >> 6;
  const int ln  = tid & 63;
  const int l15 = ln & 15;
  const int q   = ln >> 4;
  const int rowBase = blockIdx.x * 128 + wv * 32;

  // ---- x B-fragments (f16), loaded once, reused for all 28 g ----
  short8 xf[2][2];
  #pragma unroll
  for (int rt = 0; rt < 2; ++rt)
    #pragma unroll
    for (int ks = 0; ks < 2; ++ks){
      const float* p = x + (rowBase + rt*16 + l15)*64 + ks*32 + q*8;
      f32x4 a = *(const f32x4*)p;
      f32x4 b = *(const f32x4*)(p + 4);
      short8 s;
      #pragma unroll
      for (int j = 0; j < 4; ++j){
        s[j]   = (short)f2h(a[j]);
        s[4+j] = (short)f2h(b[j]);
      }
      xf[rt][ks] = s;
    }

  // ---- hoisted swizzled fragment offsets (g-invariant, uint4 units) ----
  int offA1[4][2], offA2[2][2];
  #pragma unroll
  for (int nt = 0; nt < 4; ++nt)
    #pragma unroll
    for (int ks = 0; ks < 2; ++ks){
      int n = nt*16 + l15;
      offA1[nt][ks] = ((n*128 + ks*64 + q*16) ^ ((n & 7) << 4)) >> 4;
    }
  #pragma unroll
  for (int nt = 0; nt < 2; ++nt)
    #pragma unroll
    for (int ks = 0; ks < 2; ++ks){
      int n2 = nt*16 + l15;
      offA2[nt][ks] = (((n2*128 + ks*64 + q*16) ^ ((n2 & 7) << 4)) >> 4) + 512;
    }

  // ---- staging: wave wv copies its 3 KiB slice of g's 12 KiB tile ----
  auto stage = [&](int g, int buf){
    const unsigned char* gb = ws + g*G_TILE_BYTES + wv*3072 + ln*16;
    uint4* lb = &wbuf[buf][wv*192];
    #pragma unroll
    for (int it = 0; it < 3; ++it){
      __builtin_amdgcn_global_load_lds(
          (const __attribute__((address_space(1))) void*)(gb + it*1024),
          (__attribute__((address_space(3))) void*)(lb + it*64), 16, 0, 0);
    }
  };

  // relu + f32->f16 pack (pkrtz pairs, r7-verified), h[0..3]<-v0, h[4..7]<-v1
  auto packrelu = [&](const f32x4& v0, const f32x4& v1) -> short8 {
    union { unsigned u[4]; short8 s; } r;
    pk16x2 t0 = __builtin_amdgcn_cvt_pkrtz(fmaxf(v0[0],0.f), fmaxf(v0[1],0.f));
    pk16x2 t1 = __builtin_amdgcn_cvt_pkrtz(fmaxf(v0[2],0.f), fmaxf(v0[3],0.f));
    pk16x2 t2 = __builtin_amdgcn_cvt_pkrtz(fmaxf(v1[0],0.f), fmaxf(v1[1],0.f));
    pk16x2 t3 = __builtin_amdgcn_cvt_pkrtz(fmaxf(v1[2],0.f), fmaxf(v1[3],0.f));
    r.u[0] = __builtin_bit_cast(unsigned, t0);
    r.u[1] = __builtin_bit_cast(unsigned, t1);
    r.u[2] = __builtin_bit_cast(unsigned, t2);
    r.u[3] = __builtin_bit_cast(unsigned, t3);
    return r.s;
  };

  // ---- one g-iteration; bC = this g's b1 C-operands, bN <- prefetch g+1 ----
  auto body = [&](int g, f32x4 (&bC)[4], f32x4 (&bN)[4]){
    const int cur = g & 1;
    if (g + 1 < GN) stage(g + 1, cur ^ 1);

    // prefetch next g's b1 C-operands (consumed next body -> latency hidden)
    const int gnext = (g + 1 < GN) ? g + 1 : GN - 1;
    #pragma unroll
    for (int nt = 0; nt < 4; ++nt)
      bN[nt] = *(const f32x4*)(b1 + gnext*64 + nt*16 + q*4);

    const uint4* wb = wbuf[cur];

    // ---------------- layer 1: h1T[n=64][r=32/wave] ----------------
    short8 a1[4][2];
    #pragma unroll
    for (int nt = 0; nt < 4; ++nt)
      #pragma unroll
      for (int ks = 0; ks < 2; ++ks)
        a1[nt][ks] = __builtin_bit_cast(short8, wb[offA1[nt][ks]]);
    f32x4 acc1[4][2];
    #pragma unroll
    for (int nt = 0; nt < 4; ++nt)
      #pragma unroll
      for (int rt = 0; rt < 2; ++rt){
        acc1[nt][rt] = mfma16f(a1[nt][0], xf[rt][0], bC[nt]);
        acc1[nt][rt] = mfma16f(a1[nt][1], xf[rt][1], acc1[nt][rt]);
      }

    // b2/W3 for this g (issued here: ~30 instr of slack before L2/L3 use)
    f32x4 b2v[2], w3v[2];
    #pragma unroll
    for (int nt = 0; nt < 2; ++nt){
      b2v[nt] = *(const f32x4*)(b2 + g*32 + nt*16 + q*4);
      w3v[nt] = *(const f32x4*)(W3 + g*32 + nt*16 + q*4);
    }

    // ---- h1 relu -> f16, packed IN REGISTERS as layer-2 B-frags ----
    // k-slot (ks, q*8+u*4+i) carries n = 32ks+16u+4q+i == acc1[2ks+u][rt][i]
    short8 bh[2][2];
    #pragma unroll
    for (int rt = 0; rt < 2; ++rt)
      #pragma unroll
      for (int ks = 0; ks < 2; ++ks)
        bh[rt][ks] = packrelu(acc1[2*ks][rt], acc1[2*ks + 1][rt]);

    // ---------------- layer 2: h2T[n2=32][r=32/wave] ----------------
    short8 a2[2][2];
    #pragma unroll
    for (int nt = 0; nt < 2; ++nt)
      #pragma unroll
      for (int ks = 0; ks < 2; ++ks)
        a2[nt][ks] = __builtin_bit_cast(short8, wb[offA2[nt][ks]]);
    f32x4 acc2[2][2];
    #pragma unroll
    for (int nt = 0; nt < 2; ++nt)
      #pragma unroll
      for (int rt = 0; rt < 2; ++rt){
        acc2[nt][rt] = mfma16f(a2[nt][0], bh[rt][0], b2v[nt]);
        acc2[nt][rt] = mfma16f(a2[nt][1], bh[rt][1], acc2[nt][rt]);
      }

    // ---------------- layer 3: dot + quarter-reduce -> LDS outb ----------------
    float bias3 = b3[g];
    #pragma unroll
    for (int rt = 0; rt < 2; ++rt){
      float p = 0.0f;
      #pragma unroll
      for (int nt = 0; nt < 2; ++nt)
        #pragma unroll
        for (int i = 0; i < 4; ++i)
          p = fmaf(fmaxf(acc2[nt][rt][i], 0.0f), w3v[nt][i], p);
      p += __shfl_xor(p, 16);
      p += __shfl_xor(p, 32);
      p += bias3;
      if (ln < 16)
        outb[(wv*32 + rt*16 + ln)*28 + g] = p;   // LDS, 2 lanes/bank = free
    }

    // drain stage + bias loads (no stores in vmcnt anymore), then barrier
    asm volatile("s_waitcnt vmcnt(0)" ::: "memory");
    __syncthreads();
  };

  // ---- prologue: stage g=0, prefetch b1(0) ----
  f32x4 b1A[4], b1B[4];
  stage(0, 0);
  #pragma unroll
  for (int nt = 0; nt < 4; ++nt)
    b1A[nt] = *(const f32x4*)(b1 + 0*64 + nt*16 + q*4);
  asm volatile("s_waitcnt vmcnt(0)" ::: "memory");
  __syncthreads();

  for (int gg = 0; gg < GN; gg += 2){
    body(gg,     b1A, b1B);
    body(gg + 1, b1B, b1A);
  }

  // ---- coalesced writeout: block's 128x28 chunk is contiguous in out ----
  const uint2* ob2 = (const uint2*)outb;
  uint2* og2 = (uint2*)(out + blockIdx.x * (128*28));
  #pragma unroll
  for (int i = 0; i < 7; ++i){
    int idx = i*256 + tid;
    og2[idx] = ob2[idx];
  }
}

extern "C" void kernel_launch(void* const* d_in, const int* in_sizes, int n_in,
                              void* d_out, int out_size, void* d_ws, size_t ws_size,
                              hipStream_t stream){
  const float* x  = (const float*)d_in[0];
  const float* W1 = (const float*)d_in[1];
  const float* b1 = (const float*)d_in[2];
  const float* W2 = (const float*)d_in[3];
  const float* b2 = (const float*)d_in[4];
  const float* W3 = (const float*)d_in[5];
  const float* b3 = (const float*)d_in[6];
  unsigned char* ws = (unsigned char*)d_ws;
  float* out = (float*)d_out;
  if (ws_size < (size_t)WS_BYTES) return;
  hipLaunchKernelGGL(prep_weights, dim3(GN), dim3(256), 0, stream, W1, W2, ws);
  hipLaunchKernelGGL(mlp_fused, dim3(1024), dim3(256), 0, stream,
                     x, b1, b2, W3, b3, ws, out);
}